// Round 1
// 1169.746 us; speedup vs baseline: 1.1712x; 1.1712x over previous
//
#include <hip/hip_runtime.h>
#include <hip/hip_bf16.h>
#include <stdint.h>

typedef __attribute__((ext_vector_type(8))) short short8;
typedef __attribute__((ext_vector_type(4))) float floatx4;

namespace {

constexpr int  BB  = 16;    // batch
constexpr int  E_  = 8;     // experts
constexpr int  CAP = 1024;  // capacity per expert (EC/E)
constexpr int  D_  = 512;   // d_model
constexpr int  F_  = 2048;  // d_ff
constexpr long EC_ = (long)E_ * CAP;   // 8192
constexpr long M_  = (long)BB * CAP;   // 16384 rows per expert

constexpr int BM = 256, BN = 256, BK = 64;
constexpr int NT = 512;                // 8 waves: 2 (M) x 4 (N)
constexpr int LDSZ = 131072;           // 2 bufs * (A 32KB + B 32KB)

static_assert(M_ % BM == 0 && D_ % BN == 0, "tile divisibility");

__device__ __forceinline__ float gelu_tanh(float x) {
    const float k0 = 0.7978845608028654f;  // sqrt(2/pi)
    const float k1 = 0.044715f;
    float u = k0 * x * (1.0f + k1 * x * x);
    float t = 1.0f - 2.0f / (__expf(2.0f * u) + 1.0f);
    return 0.5f * x * (1.0f + t);
}

template <int I0, int J0>
__device__ __forceinline__ void mfma_quad(floatx4 (&acc)[8][4],
                                          const short8 (&af)[8],
                                          const short8 (&bf)[4]) {
#pragma unroll
    for (int i = 0; i < 4; ++i)
#pragma unroll
        for (int j = 0; j < 2; ++j) {
            floatx4 c = acc[I0 + i][J0 + j];
            c = __builtin_amdgcn_mfma_f32_16x16x32_bf16(af[i * 2 + 0], bf[j * 2 + 0], c, 0, 0, 0);
            c = __builtin_amdgcn_mfma_f32_16x16x32_bf16(af[i * 2 + 1], bf[j * 2 + 1], c, 0, 0, 0);
            acc[I0 + i][J0 + j] = c;
        }
}

// Stage unit U of K-tile TILE. U: 0=A-half0, 1=B-half0, 2=A-half1, 3=B-half1.
// Linear LDS dest (global_load_lds requirement); the swizzle lives in the
// per-lane global source offset (sk), matched by the XOR on the ds_read side.
#define STAGE_UNIT(U, TILE)                                                         \
    do {                                                                            \
        const int t_ = (TILE);                                                      \
        if (t_ < nK) {                                                              \
            const long ko_ = (long)t_ * (2 * BK);                                   \
            char* const d_ = (((U) & 1) ? BsB : AsB) + (t_ & 1) * 32768 +           \
                             ((U) >> 1) * 16384 + wv2 * 1024;                       \
            const char* const gb_ = ((U) & 1) ? (const char*)Be : (const char*)Ae;  \
            const int o0_ = ((U) & 1) ? boff[(U) >> 1][0] : aoff[(U) >> 1][0];      \
            const int o1_ = ((U) & 1) ? boff[(U) >> 1][1] : aoff[(U) >> 1][1];      \
            __builtin_amdgcn_global_load_lds(                                       \
                (const __attribute__((address_space(1))) void*)(gb_ + o0_ + ko_),   \
                (__attribute__((address_space(3))) void*)d_, 16, 0, 0);             \
            __builtin_amdgcn_global_load_lds(                                       \
                (const __attribute__((address_space(1))) void*)(gb_ + o1_ + ko_),   \
                (__attribute__((address_space(3))) void*)(d_ + 1024), 16, 0, 0);    \
        }                                                                           \
    } while (0)

// 256x256 8-phase (4 phases/K-tile, 2 K-tiles in flight) bf16 GEMM, B^T input.
//   A rows:  addr = e*sAe + b*sAb + c*K       (m = b*CAP + c, row length == K)
//   B rows:  addr = e*sBe + n*ldb + k         (N x K, k-contiguous)
//   Out:     addr = e*sOe + b*sOb + c*ldo + n
// EPI: 0 = +bias, gelu, bf16 store   1 = +bias, f32 store   2 = f32 accumulate
template <int EPI>
__global__ __launch_bounds__(NT, 2) void gemm8p(
    const __hip_bfloat16* __restrict__ A,
    const __hip_bfloat16* __restrict__ Bt,
    const float* __restrict__ bias, void* __restrict__ Out,
    const int K, const int ldb, const int ldo,
    const long sAb, const long sAe,
    const long sBe, const int biasE,
    const long sOb, const long sOe)
{
    extern __shared__ char smem[];
    char* const AsB = smem;            // [2][256][64] bf16 (32KB per buf)
    char* const BsB = smem + 65536;

    // bijective XCD swizzle on the flattened grid (nwg % 8 == 0 by construction)
    const int gx = (int)gridDim.x, gy = (int)gridDim.y;
    const int nwg = gx * gy * (int)gridDim.z;
    int id = (int)blockIdx.x + gx * ((int)blockIdx.y + gy * (int)blockIdx.z);
    id = (id & 7) * (nwg >> 3) + (id >> 3);
    const int nt = id % gx;
    const int mt = (id / gx) % gy;
    const int e  = id / (gx * gy);
    const int m0 = mt * BM;
    const int n0 = nt * BN;

    const int tid  = (int)threadIdx.x;
    const int lane = tid & 63;
    const int w    = tid >> 6;
    const int wv2  = w * 2;
    const int wr   = w >> 2;          // 0..1: wave row (M)
    const int wc   = w & 3;           // 0..3: wave col (N)
    const int fr   = lane & 15;
    const int fq   = lane >> 4;

    const int nK = K >> 6;            // K-tiles of 64

    const __hip_bfloat16* const Ae = A  + (long)e * sAe;
    const __hip_bfloat16* const Be = Bt + (long)e * sBe + (long)n0 * ldb;

    // staging: per wave-instruction 64 lanes x 16B = 8 rows x 128B (linear LDS).
    // per-lane swizzled source column so that a ((row&7)<<4)-XOR read is correct.
    const int sk = ((lane & 7) ^ (lane >> 3)) << 3;   // element offset in row
    int aoff[2][2], boff[2][2];                       // [half][t] byte offsets
#pragma unroll
    for (int half = 0; half < 2; ++half)
#pragma unroll
        for (int t = 0; t < 2; ++t) {
            const int rit = half * 128 + (wv2 + t) * 8 + (lane >> 3);
            const int mg  = m0 + rit;
            const int b   = mg >> 10;             // CAP = 1024
            const int c   = mg & (CAP - 1);
            aoff[half][t] = (int)(((long)b * sAb + (long)c * K + sk) * 2);
            boff[half][t] = (int)(((long)rit * ldb + sk) * 2);
        }

    // ds_read side: logical col-byte cb -> physical cb ^ ((row&7)<<4)
    const int xm  = (fr & 7) << 4;
    const int cb0 = (fq << 4) ^ xm;          // k-step 0
    const int cb1 = (64 | (fq << 4)) ^ xm;   // k-step 1
    const long rowA = (long)(wr * 128 + fr) * 128;
    const long rowB = (long)(wc * 64 + fr) * 128;

    floatx4 acc[8][4] = {};

    // prologue: tile0 complete + A0,B0 of tile1 (6 units = 12 loads)
    STAGE_UNIT(0, 0); STAGE_UNIT(1, 0); STAGE_UNIT(2, 0); STAGE_UNIT(3, 0);
    STAGE_UNIT(0, 1); STAGE_UNIT(1, 1);
    if (nK >= 2) asm volatile("s_waitcnt vmcnt(4)" ::: "memory");
    else         asm volatile("s_waitcnt vmcnt(0)" ::: "memory");
    __builtin_amdgcn_s_barrier();
    asm volatile("" ::: "memory");

    for (int kt = 0; kt < nK; ++kt) {
        const char* const asb = AsB + (kt & 1) * 32768 + rowA;
        const char* const bsb = BsB + (kt & 1) * 32768 + rowB;
        short8 a0[8], a1[8], b0[4], b1[4];

        // phase 1: read A-lo + B-lo; stage A1(kt+1); Q00 = a0 x b0
#pragma unroll
        for (int i = 0; i < 4; ++i) {
            a0[i * 2 + 0] = *(const short8*)(asb + i * 2048 + cb0);
            a0[i * 2 + 1] = *(const short8*)(asb + i * 2048 + cb1);
        }
#pragma unroll
        for (int j = 0; j < 2; ++j) {
            b0[j * 2 + 0] = *(const short8*)(bsb + j * 2048 + cb0);
            b0[j * 2 + 1] = *(const short8*)(bsb + j * 2048 + cb1);
        }
        STAGE_UNIT(2, kt + 1);
        __builtin_amdgcn_s_barrier();
        asm volatile("s_waitcnt lgkmcnt(0)" ::: "memory");
        __builtin_amdgcn_sched_barrier(0);
        __builtin_amdgcn_s_setprio(1);
        mfma_quad<0, 0>(acc, a0, b0);
        __builtin_amdgcn_s_setprio(0);
        __builtin_amdgcn_sched_barrier(0);
        __builtin_amdgcn_s_barrier();
        asm volatile("" ::: "memory");

        // phase 2: read A-hi; stage B1(kt+1); Q10 = a1 x b0
#pragma unroll
        for (int i = 0; i < 4; ++i) {
            a1[i * 2 + 0] = *(const short8*)(asb + (i + 4) * 2048 + cb0);
            a1[i * 2 + 1] = *(const short8*)(asb + (i + 4) * 2048 + cb1);
        }
        STAGE_UNIT(3, kt + 1);
        __builtin_amdgcn_s_barrier();
        asm volatile("s_waitcnt lgkmcnt(0)" ::: "memory");
        __builtin_amdgcn_sched_barrier(0);
        __builtin_amdgcn_s_setprio(1);
        mfma_quad<4, 0>(acc, a1, b0);
        __builtin_amdgcn_s_setprio(0);
        __builtin_amdgcn_sched_barrier(0);
        __builtin_amdgcn_s_barrier();
        asm volatile("" ::: "memory");

        // phase 3: read B-hi; stage A0(kt+2) (A-lo reads finished in ph1/ph2); Q01 = a0 x b1
#pragma unroll
        for (int j = 0; j < 2; ++j) {
            b1[j * 2 + 0] = *(const short8*)(bsb + (j + 2) * 2048 + cb0);
            b1[j * 2 + 1] = *(const short8*)(bsb + (j + 2) * 2048 + cb1);
        }
        STAGE_UNIT(0, kt + 2);
        __builtin_amdgcn_s_barrier();
        asm volatile("s_waitcnt lgkmcnt(0)" ::: "memory");
        __builtin_amdgcn_sched_barrier(0);
        __builtin_amdgcn_s_setprio(1);
        mfma_quad<0, 2>(acc, a0, b1);
        __builtin_amdgcn_s_setprio(0);
        __builtin_amdgcn_sched_barrier(0);
        __builtin_amdgcn_s_barrier();
        asm volatile("" ::: "memory");

        // phase 4: stage B0(kt+2); K-tile boundary (counted vmcnt); Q11 = a1 x b1
        STAGE_UNIT(1, kt + 2);
        if (kt + 2 < nK) asm volatile("s_waitcnt vmcnt(4)" ::: "memory");
        else             asm volatile("s_waitcnt vmcnt(0)" ::: "memory");
        __builtin_amdgcn_s_barrier();
        asm volatile("" ::: "memory");
        __builtin_amdgcn_s_setprio(1);
        mfma_quad<4, 2>(acc, a1, b1);
        __builtin_amdgcn_s_setprio(0);
        __builtin_amdgcn_s_barrier();
        asm volatile("" ::: "memory");
    }

    // epilogue: C/D layout col = lane&15, row = (lane>>4)*4 + r
    float bv[4];
#pragma unroll
    for (int j = 0; j < 4; ++j) {
        if constexpr (EPI != 2)
            bv[j] = bias[(long)e * biasE + n0 + wc * 64 + j * 16 + fr];
        else
            bv[j] = 0.0f;
    }
#pragma unroll
    for (int i = 0; i < 8; ++i) {
#pragma unroll
        for (int r = 0; r < 4; ++r) {
            const int mg = m0 + wr * 128 + i * 16 + fq * 4 + r;
            const int b  = mg >> 10;
            const int c  = mg & (CAP - 1);
            const long ro = (long)b * sOb + (long)e * sOe + (long)c * ldo;
#pragma unroll
            for (int j = 0; j < 4; ++j) {
                const int ng = n0 + wc * 64 + j * 16 + fr;
                if constexpr (EPI == 0) {
                    ((__hip_bfloat16*)Out)[ro + ng] =
                        __float2bfloat16(gelu_tanh(acc[i][j][r] + bv[j]));
                } else if constexpr (EPI == 1) {
                    ((float*)Out)[ro + ng] = acc[i][j][r] + bv[j];
                } else {
                    ((float*)Out)[ro + ng] += acc[i][j][r];
                }
            }
        }
    }
}

__global__ __launch_bounds__(256) void cvt_f32_bf16(
    const float* __restrict__ in, __hip_bfloat16* __restrict__ out, const long n)
{
    long i = ((long)blockIdx.x * blockDim.x + threadIdx.x) * 4;
    const long stride = (long)gridDim.x * blockDim.x * 4;
    for (; i < n; i += stride) {
        const float4 v = *(const float4*)(in + i);
        __hip_bfloat16 t0 = __float2bfloat16(v.x);
        __hip_bfloat16 t1 = __float2bfloat16(v.y);
        __hip_bfloat16 t2 = __float2bfloat16(v.z);
        __hip_bfloat16 t3 = __float2bfloat16(v.w);
        ushort4 o;
        o.x = *(unsigned short*)&t0;
        o.y = *(unsigned short*)&t1;
        o.z = *(unsigned short*)&t2;
        o.w = *(unsigned short*)&t3;
        *(ushort4*)(out + i) = o;
    }
}

// per-expert transpose (R x Cc) fp32 -> (Cc x R) bf16
__global__ __launch_bounds__(256) void transpose_cvt(
    const float* __restrict__ in, __hip_bfloat16* __restrict__ out,
    const int R, const int Cc)
{
    __shared__ float tile[32][33];
    const int e = blockIdx.z;
    const float* pin = in + (long)e * R * Cc;
    __hip_bfloat16* pout = out + (long)e * R * Cc;
    const int c0 = blockIdx.x * 32;
    const int r0 = blockIdx.y * 32;
    const int tx = threadIdx.x & 31;
    const int ty = threadIdx.x >> 5;  // 0..7
#pragma unroll
    for (int rr = ty; rr < 32; rr += 8)
        tile[rr][tx] = pin[(long)(r0 + rr) * Cc + c0 + tx];
    __syncthreads();
#pragma unroll
    for (int rr = ty; rr < 32; rr += 8)
        pout[(long)(c0 + rr) * R + r0 + tx] = __float2bfloat16(tile[tx][rr]);
}

}  // namespace

extern "C" void kernel_launch(void* const* d_in, const int* in_sizes, int n_in,
                              void* d_out, int out_size, void* d_ws, size_t ws_size,
                              hipStream_t stream) {
    const float* x  = (const float*)d_in[0];
    const float* w1 = (const float*)d_in[1];
    const float* b1 = (const float*)d_in[2];
    const float* w2 = (const float*)d_in[3];
    const float* b2 = (const float*)d_in[4];
    float* out = (float*)d_out;

    const long nX  = (long)BB * EC_ * D_;  // 67,108,864
    const long nW1 = (long)E_ * D_ * F_;   //  8,388,608
    const long nW2 = nW1;

    __hip_bfloat16* xb  = (__hip_bfloat16*)d_ws;
    __hip_bfloat16* w1t = xb + nX;
    __hip_bfloat16* w2t = w1t + nW1;
    __hip_bfloat16* h   = w2t + nW2;

    const size_t fixed = (size_t)(nX + nW1 + nW2) * 2;  // 160 MiB

    // largest F-chunk whose h-buffer fits the workspace (must be % BN == 0)
    int Fc = 0;
    for (int cand : {2048, 1024, 512, 256}) {
        size_t need = fixed + (size_t)BB * EC_ * cand * 2;
        if (need <= ws_size) { Fc = cand; break; }
    }
    if (Fc == 0) return;  // workspace too small — fail visibly

    // 128 KiB dynamic LDS needs the attribute raised once (host-side; capture-safe)
    static bool attr_done = false;
    if (!attr_done) {
        hipFuncSetAttribute(reinterpret_cast<const void*>(&gemm8p<0>),
                            hipFuncAttributeMaxDynamicSharedMemorySize, LDSZ);
        hipFuncSetAttribute(reinterpret_cast<const void*>(&gemm8p<1>),
                            hipFuncAttributeMaxDynamicSharedMemorySize, LDSZ);
        hipFuncSetAttribute(reinterpret_cast<const void*>(&gemm8p<2>),
                            hipFuncAttributeMaxDynamicSharedMemorySize, LDSZ);
        attr_done = true;
    }

    // 1) x -> bf16
    cvt_f32_bf16<<<dim3(32768), dim3(256), 0, stream>>>(x, xb, nX);
    // 2) w1 (E,D,F) -> w1t (E,F,D) bf16
    transpose_cvt<<<dim3(F_ / 32, D_ / 32, E_), dim3(256), 0, stream>>>(w1, w1t, D_, F_);
    // 3) w2 (E,F,D) -> w2t (E,D,F) bf16
    transpose_cvt<<<dim3(D_ / 32, F_ / 32, E_), dim3(256), 0, stream>>>(w2, w2t, F_, D_);

    for (int f0 = 0; f0 < F_; f0 += Fc) {
        // GEMM1 chunk: h(b,e,c, 0..Fc) = gelu(x @ w1[:, f0:f0+Fc] + b1[f0:...])
        gemm8p<0><<<dim3(Fc / BN, (int)(M_ / BM), E_), dim3(NT), LDSZ, stream>>>(
            xb, w1t + (long)f0 * D_, b1 + f0, h,
            /*K=*/D_, /*ldb=*/D_, /*ldo=*/Fc,
            /*sAb=*/EC_ * D_, /*sAe=*/(long)CAP * D_,
            /*sBe=*/(long)F_ * D_, /*biasE=*/F_,
            /*sOb=*/(long)E_ * CAP * Fc, /*sOe=*/(long)CAP * Fc);

        // GEMM2 chunk: y (+)= h_chunk @ w2[f0:f0+Fc, :]  (+ b2 on first chunk)
        if (f0 == 0) {
            gemm8p<1><<<dim3(D_ / BN, (int)(M_ / BM), E_), dim3(NT), LDSZ, stream>>>(
                h, w2t + f0, b2, out,
                /*K=*/Fc, /*ldb=*/F_, /*ldo=*/D_,
                /*sAb=*/(long)E_ * CAP * Fc, /*sAe=*/(long)CAP * Fc,
                /*sBe=*/(long)D_ * F_, /*biasE=*/D_,
                /*sOb=*/EC_ * D_, /*sOe=*/(long)CAP * D_);
        } else {
            gemm8p<2><<<dim3(D_ / BN, (int)(M_ / BM), E_), dim3(NT), LDSZ, stream>>>(
                h, w2t + f0, nullptr, out,
                /*K=*/Fc, /*ldb=*/F_, /*ldo=*/D_,
                /*sAb=*/(long)E_ * CAP * Fc, /*sAe=*/(long)CAP * Fc,
                /*sBe=*/(long)D_ * F_, /*biasE=*/D_,
                /*sOb=*/EC_ * D_, /*sOe=*/(long)CAP * D_);
        }
    }
}